// Round 2
// baseline (1300.510 us; speedup 1.0000x reference)
//
#include <hip/hip_runtime.h>
#include <hip/hip_bf16.h>
#include <math.h>

#define Bn   384
#define INn  512
#define OUTn 384

typedef __bf16 bf16x8 __attribute__((ext_vector_type(8)));
typedef __bf16 bf16x4 __attribute__((ext_vector_type(4)));
typedef float  f32x4  __attribute__((ext_vector_type(4)));

// Device-global scratch (no assumption about ws_size).
__device__ __bf16 g_Wbf[OUTn * INn];                 // W cast to bf16, [o][i]
__device__ float  g_sp [OUTn * INn];                 // softplus(sigma_weight)
__device__ float  g_d  [Bn * OUTn];                  // s1+s3 diagonal vector
__device__ float  g_t  [Bn * INn];                   // diag(sigma_b), fp32
__device__ __bf16 g_U  [(size_t)Bn * OUTn * INn];    // U[b][p][i] = sum_j sigma[b,i,j]*W[p,j]

// ---------------------------------------------------------------------------
// prep: Wbf = bf16(W); sp = softplus(sigma_weight)
// ---------------------------------------------------------------------------
__global__ __launch_bounds__(256) void prep_kernel(const float* __restrict__ W,
                                                   const float* __restrict__ sw) {
    int idx = blockIdx.x * 256 + threadIdx.x;
    if (idx < OUTn * INn) {
        g_Wbf[idx] = (__bf16)W[idx];
        float x = sw[idx];
        g_sp[idx] = (x > 20.f) ? x : log1pf(expf(x));
    }
}

// ---------------------------------------------------------------------------
// passA (barrier-free): U[b][p][i] = sum_j sigma[b,i,j] * W[p,j]
// grid (16 i-tiles of 32, 384 b), 256 thr = 4 waves. NO LDS, NO barriers:
//  - A (sigma rows): loaded straight into MFMA fragments, f32->bf16 in-reg.
//    All 4 waves read IDENTICAL sigma addresses -> L1 broadcast; each block's
//    32-row tile is disjoint -> sigma fetched from HBM exactly once.
//  - B (W rows): per-wave 96-p slice streamed from L2 (W is chip-resident).
//  - diag(sigma) extracted fp32-exact from the already-loaded A words (wave 0).
// MFMA 16x16x32: A frag = [row=l15][k=quad*8+j]; D = [row=quad*4+r][col=l15].
// ---------------------------------------------------------------------------
__global__ __launch_bounds__(256, 3) void passA_kernel(const float* __restrict__ sigma) {
    const int it   = blockIdx.x;    // 0..15
    const int b    = blockIdx.y;    // 0..383
    const int tid  = threadIdx.x;
    const int wave = tid >> 6, lane = tid & 63;
    const int quad = lane >> 4, l15 = lane & 15;
    const int i0     = it * 32;
    const int p_base = wave * 96;   // 4 waves x 96 = 384 p

    const float* sigb = sigma + (size_t)b * (INn * INn);

    f32x4 acc[2][6];
#pragma unroll
    for (int mi = 0; mi < 2; ++mi)
#pragma unroll
        for (int nf = 0; nf < 6; ++nf) acc[mi][nf] = (f32x4){0.f, 0.f, 0.f, 0.f};

    for (int kc = 0; kc < INn; kc += 32) {
        bf16x8 afr[2];
#pragma unroll
        for (int mi = 0; mi < 2; ++mi) {
            const int row = i0 + mi * 16 + l15;
            const float* ap = sigb + (size_t)row * INn + kc + quad * 8;
            float4 a0 = *(const float4*)ap;
            float4 a1 = *(const float4*)(ap + 4);
            if (wave == 0) {                       // fp32-exact diagonal, once
                const int j = row - (kc + quad * 8);
                if (j >= 0 && j < 8) {
                    float dv = (j==0)?a0.x:(j==1)?a0.y:(j==2)?a0.z:(j==3)?a0.w
                             :(j==4)?a1.x:(j==5)?a1.y:(j==6)?a1.z:a1.w;
                    g_t[b * INn + row] = dv;
                }
            }
            bf16x8 t;
            t[0]=(__bf16)a0.x; t[1]=(__bf16)a0.y; t[2]=(__bf16)a0.z; t[3]=(__bf16)a0.w;
            t[4]=(__bf16)a1.x; t[5]=(__bf16)a1.y; t[6]=(__bf16)a1.z; t[7]=(__bf16)a1.w;
            afr[mi] = t;
        }
#pragma unroll
        for (int nf = 0; nf < 6; ++nf) {
            const __bf16* bp = g_Wbf + (size_t)(p_base + nf * 16 + l15) * INn + kc + quad * 8;
            bf16x8 bfr = *(const bf16x8*)bp;
            acc[0][nf] = __builtin_amdgcn_mfma_f32_16x16x32_bf16(afr[0], bfr, acc[0][nf], 0, 0, 0);
            acc[1][nf] = __builtin_amdgcn_mfma_f32_16x16x32_bf16(afr[1], bfr, acc[1][nf], 0, 0, 0);
        }
    }

    // store U[b][p][i] bf16: lane holds D[i=quad*4+r][p=l15] -> 8B stores,
    // quads cover 16 consecutive i per p-row.
    __bf16* Ub = g_U + (size_t)b * (OUTn * INn);
#pragma unroll
    for (int mi = 0; mi < 2; ++mi) {
        const int ib = i0 + mi * 16 + quad * 4;
#pragma unroll
        for (int nf = 0; nf < 6; ++nf) {
            const int p = p_base + nf * 16 + l15;
            bf16x4 v;
            v[0] = (__bf16)acc[mi][nf][0];
            v[1] = (__bf16)acc[mi][nf][1];
            v[2] = (__bf16)acc[mi][nf][2];
            v[3] = (__bf16)acc[mi][nf][3];
            *(bf16x4*)(Ub + (size_t)p * INn + ib) = v;
        }
    }
}

// ---------------------------------------------------------------------------
// k2: mu_f[b,o] = mu[b,:]·W[o,:] + bias[o]
//     d[b,o]   = sum_i (diag_sigma[b,i] + mu[b,i]^2) * sp[o,i] + (o==b)*sbias[o]
// ---------------------------------------------------------------------------
__global__ __launch_bounds__(256) void k2_kernel(const float* __restrict__ mu,
                                                 const float* __restrict__ W,
                                                 const float* __restrict__ bias,
                                                 const float* __restrict__ sbias,
                                                 float* __restrict__ out_muf) {
    const int b  = blockIdx.x;
    const int oq = blockIdx.y;   // 0..3
    __shared__ __align__(16) float muL[INn];
    __shared__ __align__(16) float tL[INn];
    const int tid = threadIdx.x;
    for (int i = tid; i < INn; i += 256) {
        float m = mu[b * INn + i];
        muL[i] = m;
        tL[i] = g_t[b * INn + i] + m * m;
    }
    __syncthreads();
    const int wave = tid >> 6, lane = tid & 63;
    const float4* Mr = (const float4*)muL;
    const float4* Tr = (const float4*)tL;
    float4 m0 = Mr[lane * 2], m1 = Mr[lane * 2 + 1];
    float4 t0 = Tr[lane * 2], t1 = Tr[lane * 2 + 1];
#pragma unroll 4
    for (int ow = 0; ow < 24; ++ow) {
        const int o = oq * 96 + wave * 24 + ow;
        const float4* Wr = (const float4*)(W + (size_t)o * INn);
        const float4* Sr = (const float4*)(g_sp + (size_t)o * INn);
        float4 w0 = Wr[lane * 2], w1 = Wr[lane * 2 + 1];
        float4 s0 = Sr[lane * 2], s1 = Sr[lane * 2 + 1];
        float mf = w0.x * m0.x + w0.y * m0.y + w0.z * m0.z + w0.w * m0.w
                 + w1.x * m1.x + w1.y * m1.y + w1.z * m1.z + w1.w * m1.w;
        float dd = s0.x * t0.x + s0.y * t0.y + s0.z * t0.z + s0.w * t0.w
                 + s1.x * t1.x + s1.y * t1.y + s1.z * t1.z + s1.w * t1.w;
#pragma unroll
        for (int off = 32; off; off >>= 1) {
            mf += __shfl_xor(mf, off, 64);
            dd += __shfl_xor(dd, off, 64);
        }
        if (lane == 0) {
            out_muf[b * OUTn + o] = mf + bias[o];
            g_d[b * OUTn + o] = dd + (o == b ? sbias[o] : 0.f);
        }
    }
}

// ---------------------------------------------------------------------------
// passB (barrier-free): out[b,o,p0+p] = sum_i Wbf[o,i] * U[b][p0+p][i]
//                       (+ d[b,o] on the o==p diagonal)
// grid (6 p-tiles of 64, 384 b), 512 thr = 8 waves. NO LDS, NO barriers:
//  - A (W rows): per-wave 48-o slice from L2 (chip-resident, reused by all
//    2304 blocks).
//  - B (U rows): all 8 waves read the IDENTICAL 64KB U tile -> L1/L2 hits
//    after first toucher; each tile read from HBM/L3 exactly once.
// ---------------------------------------------------------------------------
__global__ __launch_bounds__(512, 4) void passB_kernel(float* __restrict__ outS) {
    const int ptile = blockIdx.x;   // 0..5
    const int b     = blockIdx.y;   // 0..383
    const int tid   = threadIdx.x;
    const int wave  = tid >> 6, lane = tid & 63;
    const int quad  = lane >> 4, l15 = lane & 15;
    const int p0     = ptile * 64;
    const int o_base = wave * 48;   // 8 waves x 48 = 384 o

    const __bf16* Ub = g_U + ((size_t)b * OUTn + p0) * INn;

    f32x4 acc[3][4];
#pragma unroll
    for (int mi = 0; mi < 3; ++mi)
#pragma unroll
        for (int nf = 0; nf < 4; ++nf) acc[mi][nf] = (f32x4){0.f, 0.f, 0.f, 0.f};

    for (int kc = 0; kc < INn; kc += 32) {
        bf16x8 afr[3];
#pragma unroll
        for (int mi = 0; mi < 3; ++mi) {
            const __bf16* ap = g_Wbf + (size_t)(o_base + mi * 16 + l15) * INn + kc + quad * 8;
            afr[mi] = *(const bf16x8*)ap;
        }
#pragma unroll
        for (int nf = 0; nf < 4; ++nf) {
            const __bf16* bp = Ub + (size_t)(nf * 16 + l15) * INn + kc + quad * 8;
            bf16x8 bfr = *(const bf16x8*)bp;
#pragma unroll
            for (int mi = 0; mi < 3; ++mi)
                acc[mi][nf] = __builtin_amdgcn_mfma_f32_16x16x32_bf16(afr[mi], bfr, acc[mi][nf], 0, 0, 0);
        }
    }

    // epilogue: add diagonal, store fp32
    float* outb = outS + (size_t)b * (OUTn * OUTn);
#pragma unroll
    for (int mi = 0; mi < 3; ++mi) {
        const int o_r = o_base + mi * 16 + quad * 4;
#pragma unroll
        for (int nf = 0; nf < 4; ++nf) {
            const int p = p0 + nf * 16 + l15;
#pragma unroll
            for (int r = 0; r < 4; ++r) {
                const int o = o_r + r;
                float v = acc[mi][nf][r];
                if (o == p) v += g_d[b * OUTn + o];
                outb[(size_t)o * OUTn + p] = v;
            }
        }
    }
}

// ---------------------------------------------------------------------------
extern "C" void kernel_launch(void* const* d_in, const int* in_sizes, int n_in,
                              void* d_out, int out_size, void* d_ws, size_t ws_size,
                              hipStream_t stream) {
    const float* mu    = (const float*)d_in[0];
    const float* sigma = (const float*)d_in[1];
    const float* W     = (const float*)d_in[2];
    const float* bias  = (const float*)d_in[3];
    const float* sw    = (const float*)d_in[4];
    const float* sbias = (const float*)d_in[5];

    float* out     = (float*)d_out;
    float* out_muf = out;                  // [384, 384]
    float* out_sig = out + Bn * OUTn;      // [384, 384, 384]

    prep_kernel<<<(OUTn * INn + 255) / 256, 256, 0, stream>>>(W, sw);
    passA_kernel<<<dim3(16, Bn), 256, 0, stream>>>(sigma);          // writes g_U, g_t
    k2_kernel<<<dim3(Bn, 4), 256, 0, stream>>>(mu, W, bias, sbias, out_muf); // writes g_d
    passB_kernel<<<dim3(6, Bn), 512, 0, stream>>>(out_sig);
}

// Round 3
// 1054.128 us; speedup vs baseline: 1.2337x; 1.2337x over previous
//
#include <hip/hip_runtime.h>
#include <hip/hip_bf16.h>
#include <math.h>

#define Bn   384
#define INn  512
#define OUTn 384

typedef __bf16 bf16x8 __attribute__((ext_vector_type(8)));
typedef __bf16 bf16x4 __attribute__((ext_vector_type(4)));
typedef float  f32x4  __attribute__((ext_vector_type(4)));

// Device-global scratch (no assumption about ws_size).
__device__ __bf16 g_Wbf[OUTn * INn];                 // W cast to bf16, [o][i]
__device__ float  g_Wt [INn * OUTn];                 // W transposed fp32, [i][o]
__device__ float  g_spt[INn * OUTn];                 // softplus(sw) transposed, [i][o]
__device__ float  g_d  [Bn * OUTn];                  // s1+s3 diagonal vector
__device__ float  g_t  [Bn * INn];                   // diag(sigma_b), fp32
__device__ __bf16 g_U  [(size_t)Bn * OUTn * INn];    // U[b][p][i] = sum_j sigma[b,i,j]*W[p,j]

// ---------------------------------------------------------------------------
// prep: Wbf = bf16(W); Wt/spt = fp32 transposes for k2
// ---------------------------------------------------------------------------
__global__ __launch_bounds__(256) void prep_kernel(const float* __restrict__ W,
                                                   const float* __restrict__ sw) {
    int idx = blockIdx.x * 256 + threadIdx.x;
    if (idx < OUTn * INn) {
        const int o = idx >> 9, i = idx & 511;   // idx = o*INn + i
        float w = W[idx];
        g_Wbf[idx] = (__bf16)w;
        g_Wt[i * OUTn + o] = w;
        float x = sw[idx];
        g_spt[i * OUTn + o] = (x > 20.f) ? x : log1pf(expf(x));
    }
}

// ---------------------------------------------------------------------------
// passA: U[b][p][i] = sum_j sigma[b,i,j] * W[p,j]   (bf16 out)
// grid (8 i-tiles of 64, 384 b), 512 thr = 8 waves.
// 2-phase pipelined K: 4 chunks of 128 j-cols, double-buffered bf16 LDS
// (2 x 64 x 136 = 34.8 KB). Next chunk's global loads issued BEFORE compute
// (T14 issue-early/write-late); sigma fetched from HBM exactly once.
// Diagonal extracted fp32-exact during staging -> g_t.
// MFMA 16x16x32: A frag [row=l15][k=quad*8+j]; D [row=quad*4+r][col=l15].
// ---------------------------------------------------------------------------
__global__ __launch_bounds__(512, 4) void passA_kernel(const float* __restrict__ sigma) {
    __shared__ __bf16 As[2][64][136];   // row stride 272B -> 2-way bank (free)

    const int it   = blockIdx.x;    // 0..7
    const int b    = blockIdx.y;    // 0..383
    const int tid  = threadIdx.x;
    const int wave = tid >> 6, lane = tid & 63;
    const int quad = lane >> 4, l15 = lane & 15;
    const int i0     = it * 64;
    const int p_base = wave * 48;   // 8 waves x 48 = 384 p
    const int srow   = tid >> 3;        // staging row 0..63
    const int scol   = (tid & 7) * 16;  // staging col (f32 elems) 0..112

    const float* sigb   = sigma + (size_t)b * (INn * INn);
    const float* srcRow = sigb + (size_t)(i0 + srow) * INn + scol;

    float4 r0, r1, r2, r3;   // staged chunk (16 f32/thread), live across compute

    auto LOAD = [&](int c) {
        const float4* p = (const float4*)(srcRow + c * 128);
        r0 = p[0]; r1 = p[1]; r2 = p[2]; r3 = p[3];
    };
    auto STORE = [&](int c, int buf) {
        // fp32-exact diagonal extraction (this thread holds sigma[b,ig,ig]?)
        const int ig   = i0 + srow;
        const int base = c * 128 + scol;
        if (ig >= base && ig < base + 16) {
            const int j = ig - base;
            float4 v = (j < 4) ? r0 : (j < 8) ? r1 : (j < 12) ? r2 : r3;
            const int e = j & 3;
            float dv = (e == 0) ? v.x : (e == 1) ? v.y : (e == 2) ? v.z : v.w;
            g_t[b * INn + ig] = dv;
        }
        bf16x8 t0, t1;
        t0[0]=(__bf16)r0.x; t0[1]=(__bf16)r0.y; t0[2]=(__bf16)r0.z; t0[3]=(__bf16)r0.w;
        t0[4]=(__bf16)r1.x; t0[5]=(__bf16)r1.y; t0[6]=(__bf16)r1.z; t0[7]=(__bf16)r1.w;
        t1[0]=(__bf16)r2.x; t1[1]=(__bf16)r2.y; t1[2]=(__bf16)r2.z; t1[3]=(__bf16)r2.w;
        t1[4]=(__bf16)r3.x; t1[5]=(__bf16)r3.y; t1[6]=(__bf16)r3.z; t1[7]=(__bf16)r3.w;
        *(bf16x8*)&As[buf][srow][scol]     = t0;
        *(bf16x8*)&As[buf][srow][scol + 8] = t1;
    };

    f32x4 acc[4][3];
#pragma unroll
    for (int mi = 0; mi < 4; ++mi)
#pragma unroll
        for (int nf = 0; nf < 3; ++nf) acc[mi][nf] = (f32x4){0.f, 0.f, 0.f, 0.f};

    auto COMPUTE = [&](int buf, int kc0) {
#pragma unroll
        for (int kcl = 0; kcl < 128; kcl += 32) {
            bf16x8 afr[4];
#pragma unroll
            for (int mi = 0; mi < 4; ++mi)
                afr[mi] = *(const bf16x8*)&As[buf][mi * 16 + l15][kcl + quad * 8];
#pragma unroll
            for (int nf = 0; nf < 3; ++nf) {
                const __bf16* bp = g_Wbf + (size_t)(p_base + nf * 16 + l15) * INn + kc0 + kcl + quad * 8;
                bf16x8 bfr = *(const bf16x8*)bp;
#pragma unroll
                for (int mi = 0; mi < 4; ++mi)
                    acc[mi][nf] = __builtin_amdgcn_mfma_f32_16x16x32_bf16(afr[mi], bfr, acc[mi][nf], 0, 0, 0);
            }
        }
    };

    // ---- pipelined K loop ----
    LOAD(0); STORE(0, 0); LOAD(1);
    __syncthreads();
    COMPUTE(0, 0);
    __syncthreads(); STORE(1, 1); LOAD(2); __syncthreads();
    COMPUTE(1, 128);
    __syncthreads(); STORE(2, 0); LOAD(3); __syncthreads();
    COMPUTE(0, 256);
    __syncthreads(); STORE(3, 1); __syncthreads();
    COMPUTE(1, 384);

    // ---- store U[b][p][i] bf16 (8B stores) ----
    __bf16* Ub = g_U + (size_t)b * (OUTn * INn);
#pragma unroll
    for (int mi = 0; mi < 4; ++mi) {
        const int ib = i0 + mi * 16 + quad * 4;
#pragma unroll
        for (int nf = 0; nf < 3; ++nf) {
            const int p = p_base + nf * 16 + l15;
            bf16x4 v;
            v[0] = (__bf16)acc[mi][nf][0];
            v[1] = (__bf16)acc[mi][nf][1];
            v[2] = (__bf16)acc[mi][nf][2];
            v[3] = (__bf16)acc[mi][nf][3];
            *(bf16x4*)(Ub + (size_t)p * INn + ib) = v;
        }
    }
}

// ---------------------------------------------------------------------------
// k2: mu_f[b,o] = mu[b,:]·W[o,:] + bias[o]
//     d[b,o]   = sum_i (diag_sigma[b,i] + mu[b,i]^2) * sp[o,i] + (o==b)*sbias[o]
// One thread per o, transposed coalesced fp32 loads, NO cross-lane reduction.
// ---------------------------------------------------------------------------
__global__ __launch_bounds__(384) void k2_kernel(const float* __restrict__ mu,
                                                 const float* __restrict__ bias,
                                                 const float* __restrict__ sbias,
                                                 float* __restrict__ out_muf) {
    const int b = blockIdx.x;
    const int t = threadIdx.x;   // = o
    __shared__ __align__(16) float muL[INn];
    __shared__ __align__(16) float tL[INn];
    for (int i = t; i < INn; i += 384) {
        float m = mu[b * INn + i];
        muL[i] = m;
        tL[i] = g_t[b * INn + i] + m * m;
    }
    __syncthreads();
    float mf = 0.f, dd = 0.f;
#pragma unroll 8
    for (int i = 0; i < INn; ++i) {
        mf += g_Wt[i * OUTn + t] * muL[i];
        dd += g_spt[i * OUTn + t] * tL[i];
    }
    out_muf[b * OUTn + t] = mf + bias[t];
    g_d[b * OUTn + t] = dd + (t == b ? sbias[t] : 0.f);
}

// ---------------------------------------------------------------------------
// passB: out[b,o,p0+p] = sum_i Wbf[o,i] * U[b][p0+p][i]  (+ d[b,o] if o==p)
// grid (6 p-tiles of 64, 384 b), 512 thr = 8 waves. Same 2-phase pipelined
// structure as passA (U already bf16 -> pure copy staging, no cvt).
// ---------------------------------------------------------------------------
__global__ __launch_bounds__(512, 4) void passB_kernel(float* __restrict__ outS) {
    __shared__ __bf16 Ut[2][64][136];

    const int ptile = blockIdx.x;   // 0..5
    const int b     = blockIdx.y;   // 0..383
    const int tid   = threadIdx.x;
    const int wave  = tid >> 6, lane = tid & 63;
    const int quad  = lane >> 4, l15 = lane & 15;
    const int p0     = ptile * 64;
    const int o_base = wave * 48;   // 8 waves x 48 = 384 o
    const int srow   = tid >> 3;        // staging row (p-local) 0..63
    const int scol   = (tid & 7) * 16;  // staging col (bf16 elems) 0..112

    const __bf16* Ub     = g_U + ((size_t)b * OUTn + p0) * INn;
    const __bf16* srcRow = Ub + (size_t)srow * INn + scol;

    bf16x8 u0, u1;   // staged chunk (32B/thread)

    auto LOAD = [&](int c) {
        const bf16x8* p = (const bf16x8*)(srcRow + c * 128);
        u0 = p[0]; u1 = p[1];
    };
    auto STORE = [&](int buf) {
        *(bf16x8*)&Ut[buf][srow][scol]     = u0;
        *(bf16x8*)&Ut[buf][srow][scol + 8] = u1;
    };

    f32x4 acc[3][4];
#pragma unroll
    for (int mi = 0; mi < 3; ++mi)
#pragma unroll
        for (int nf = 0; nf < 4; ++nf) acc[mi][nf] = (f32x4){0.f, 0.f, 0.f, 0.f};

    auto COMPUTE = [&](int buf, int kc0) {
#pragma unroll
        for (int kcl = 0; kcl < 128; kcl += 32) {
            bf16x8 afr[3];
#pragma unroll
            for (int mi = 0; mi < 3; ++mi) {
                const __bf16* ap = g_Wbf + (size_t)(o_base + mi * 16 + l15) * INn + kc0 + kcl + quad * 8;
                afr[mi] = *(const bf16x8*)ap;
            }
#pragma unroll
            for (int nf = 0; nf < 4; ++nf) {
                bf16x8 bfr = *(const bf16x8*)&Ut[buf][nf * 16 + l15][kcl + quad * 8];
#pragma unroll
                for (int mi = 0; mi < 3; ++mi)
                    acc[mi][nf] = __builtin_amdgcn_mfma_f32_16x16x32_bf16(afr[mi], bfr, acc[mi][nf], 0, 0, 0);
            }
        }
    };

    // ---- pipelined K loop ----
    LOAD(0); STORE(0); LOAD(1);
    __syncthreads();
    COMPUTE(0, 0);
    __syncthreads(); STORE(1); LOAD(2); __syncthreads();
    COMPUTE(1, 128);
    __syncthreads(); STORE(0); LOAD(3); __syncthreads();
    COMPUTE(0, 256);
    __syncthreads(); STORE(1); __syncthreads();
    COMPUTE(1, 384);

    // ---- epilogue: add diagonal, store fp32 ----
    float* outb = outS + (size_t)b * (OUTn * OUTn);
#pragma unroll
    for (int mi = 0; mi < 3; ++mi) {
        const int o_r = o_base + mi * 16 + quad * 4;
#pragma unroll
        for (int nf = 0; nf < 4; ++nf) {
            const int p = p0 + nf * 16 + l15;
#pragma unroll
            for (int r = 0; r < 4; ++r) {
                const int o = o_r + r;
                float v = acc[mi][nf][r];
                if (o == p) v += g_d[b * OUTn + o];
                outb[(size_t)o * OUTn + p] = v;
            }
        }
    }
}

// ---------------------------------------------------------------------------
extern "C" void kernel_launch(void* const* d_in, const int* in_sizes, int n_in,
                              void* d_out, int out_size, void* d_ws, size_t ws_size,
                              hipStream_t stream) {
    const float* mu    = (const float*)d_in[0];
    const float* sigma = (const float*)d_in[1];
    const float* W     = (const float*)d_in[2];
    const float* bias  = (const float*)d_in[3];
    const float* sw    = (const float*)d_in[4];
    const float* sbias = (const float*)d_in[5];

    float* out     = (float*)d_out;
    float* out_muf = out;                  // [384, 384]
    float* out_sig = out + Bn * OUTn;      // [384, 384, 384]

    prep_kernel<<<(OUTn * INn + 255) / 256, 256, 0, stream>>>(W, sw);
    passA_kernel<<<dim3(8, Bn), 512, 0, stream>>>(sigma);                    // g_U, g_t
    k2_kernel<<<Bn, 384, 0, stream>>>(mu, bias, sbias, out_muf);             // g_d
    passB_kernel<<<dim3(6, Bn), 512, 0, stream>>>(out_sig);
}

// Round 4
// 998.239 us; speedup vs baseline: 1.3028x; 1.0560x over previous
//
#include <hip/hip_runtime.h>
#include <hip/hip_bf16.h>
#include <math.h>

#define Bn   384
#define INn  512
#define OUTn 384

typedef __bf16 bf16x8 __attribute__((ext_vector_type(8)));
typedef __bf16 bf16x4 __attribute__((ext_vector_type(4)));
typedef float  f32x4  __attribute__((ext_vector_type(4)));

// Device-global scratch (no assumption about ws_size).
// g_Wf: W in MFMA-fragment order: f = ((((o>>4)*16 + (i>>5))*4 + ((i>>3)&3))*16 + (o&15))*8 + (i&7)
//       -> a wave's fragment load is lane*16B contiguous (1KB/instr).
__device__ __bf16 g_Wf [OUTn * INn];
__device__ float  g_Wt [INn * OUTn];                 // W transposed fp32, [i][o]
__device__ float  g_spt[INn * OUTn];                 // softplus(sw) transposed, [i][o]
__device__ float  g_d  [Bn * OUTn];                  // s1+s3 diagonal vector
__device__ float  g_t  [Bn * INn];                   // diag(sigma_b), fp32
// U2[b][i>>2][p][i&3] : matches the MFMA D-fragment (lane holds 4 consecutive i
// for one p) -> passA stores are fully-covered 128B lines; passB B-frag loads
// are 4 fully-used 128B lines per instruction.
__device__ __bf16 g_U  [(size_t)Bn * OUTn * INn];

// ---------------------------------------------------------------------------
// prep: g_Wf (fragment-ordered bf16 W); g_Wt/g_spt fp32 transposes for k2
// ---------------------------------------------------------------------------
__global__ __launch_bounds__(256) void prep_kernel(const float* __restrict__ W,
                                                   const float* __restrict__ sw) {
    int idx = blockIdx.x * 256 + threadIdx.x;
    if (idx < OUTn * INn) {
        const int o = idx >> 9, i = idx & 511;   // idx = o*INn + i
        float w = W[idx];
        const int f = ((((o >> 4) * 16 + (i >> 5)) * 4 + ((i >> 3) & 3)) * 16 + (o & 15)) * 8 + (i & 7);
        g_Wf[f] = (__bf16)w;
        g_Wt[i * OUTn + o] = w;
        float x = sw[idx];
        g_spt[i * OUTn + o] = (x > 20.f) ? x : log1pf(expf(x));
    }
}

// ---------------------------------------------------------------------------
// passA: U2[b][i>>2][p][i&3] = sum_j sigma[b,i,j] * W[p,j]   (bf16 out)
// grid (8 i-tiles of 64, 384 b), 512 thr = 8 waves.
// 2-phase pipelined K: 4 chunks of 128 j, double-buffered LDS (2x64x136 bf16).
// W fragments from g_Wf (1KB contiguous per instr). U2 stores are full-line.
// Diagonal extracted fp32-exact during staging -> g_t.
// MFMA 16x16x32: A frag [row=l15][k=quad*8+j]; D [row=quad*4+r][col=l15].
// ---------------------------------------------------------------------------
__global__ __launch_bounds__(512, 4) void passA_kernel(const float* __restrict__ sigma) {
    __shared__ __bf16 As[2][64][136];

    const int it   = blockIdx.x;    // 0..7
    const int b    = blockIdx.y;    // 0..383
    const int tid  = threadIdx.x;
    const int wave = tid >> 6, lane = tid & 63;
    const int quad = lane >> 4, l15 = lane & 15;
    const int i0     = it * 64;
    const int p_base = wave * 48;   // 8 waves x 48 = 384 p
    const int srow   = tid >> 3;        // staging row 0..63
    const int scol   = (tid & 7) * 16;  // staging col (f32 elems) 0..112

    const float* sigb   = sigma + (size_t)b * (INn * INn);
    const float* srcRow = sigb + (size_t)(i0 + srow) * INn + scol;

    float4 r0, r1, r2, r3;   // staged chunk (16 f32/thread)

    auto LOAD = [&](int c) {
        const float4* p = (const float4*)(srcRow + c * 128);
        r0 = p[0]; r1 = p[1]; r2 = p[2]; r3 = p[3];
    };
    auto STORE = [&](int c, int buf) {
        const int ig   = i0 + srow;
        const int base = c * 128 + scol;
        if (ig >= base && ig < base + 16) {          // fp32-exact diagonal
            const int j = ig - base;
            float4 v = (j < 4) ? r0 : (j < 8) ? r1 : (j < 12) ? r2 : r3;
            const int e = j & 3;
            float dv = (e == 0) ? v.x : (e == 1) ? v.y : (e == 2) ? v.z : v.w;
            g_t[b * INn + ig] = dv;
        }
        bf16x8 t0, t1;
        t0[0]=(__bf16)r0.x; t0[1]=(__bf16)r0.y; t0[2]=(__bf16)r0.z; t0[3]=(__bf16)r0.w;
        t0[4]=(__bf16)r1.x; t0[5]=(__bf16)r1.y; t0[6]=(__bf16)r1.z; t0[7]=(__bf16)r1.w;
        t1[0]=(__bf16)r2.x; t1[1]=(__bf16)r2.y; t1[2]=(__bf16)r2.z; t1[3]=(__bf16)r2.w;
        t1[4]=(__bf16)r3.x; t1[5]=(__bf16)r3.y; t1[6]=(__bf16)r3.z; t1[7]=(__bf16)r3.w;
        *(bf16x8*)&As[buf][srow][scol]     = t0;
        *(bf16x8*)&As[buf][srow][scol + 8] = t1;
    };

    f32x4 acc[4][3];
#pragma unroll
    for (int mi = 0; mi < 4; ++mi)
#pragma unroll
        for (int nf = 0; nf < 3; ++nf) acc[mi][nf] = (f32x4){0.f, 0.f, 0.f, 0.f};

    auto COMPUTE = [&](int buf, int kc0) {
#pragma unroll
        for (int kcl = 0; kcl < 128; kcl += 32) {
            bf16x8 afr[4];
#pragma unroll
            for (int mi = 0; mi < 4; ++mi)
                afr[mi] = *(const bf16x8*)&As[buf][mi * 16 + l15][kcl + quad * 8];
#pragma unroll
            for (int nf = 0; nf < 3; ++nf) {
                const int ot   = wave * 3 + nf;
                const int kc32 = (kc0 + kcl) >> 5;
                const __bf16* bp = g_Wf + ((((size_t)(ot * 16 + kc32) * 4 + quad) * 16 + l15) << 3);
                bf16x8 bfr = *(const bf16x8*)bp;
#pragma unroll
                for (int mi = 0; mi < 4; ++mi)
                    acc[mi][nf] = __builtin_amdgcn_mfma_f32_16x16x32_bf16(afr[mi], bfr, acc[mi][nf], 0, 0, 0);
            }
        }
    };

    // ---- pipelined K loop ----
    LOAD(0); STORE(0, 0); LOAD(1);
    __syncthreads();
    COMPUTE(0, 0);
    __syncthreads(); STORE(1, 1); LOAD(2); __syncthreads();
    COMPUTE(1, 128);
    __syncthreads(); STORE(2, 0); LOAD(3); __syncthreads();
    COMPUTE(0, 256);
    __syncthreads(); STORE(3, 1); __syncthreads();
    COMPUTE(1, 384);

    // ---- store U2: full-line coalesced (lane*8B contiguous per instr) ----
    __bf16* Ub = g_U + (size_t)b * (OUTn * INn);
#pragma unroll
    for (int mi = 0; mi < 4; ++mi) {
        const int i4 = ((i0 + mi * 16) >> 2) + quad;   // i-group index
#pragma unroll
        for (int nf = 0; nf < 3; ++nf) {
            const int p = p_base + nf * 16 + l15;
            bf16x4 v;
            v[0] = (__bf16)acc[mi][nf][0];
            v[1] = (__bf16)acc[mi][nf][1];
            v[2] = (__bf16)acc[mi][nf][2];
            v[3] = (__bf16)acc[mi][nf][3];
            *(bf16x4*)(Ub + ((size_t)i4 * OUTn + p) * 4) = v;
        }
    }
}

// ---------------------------------------------------------------------------
// k2: mu_f[b,o] = mu[b,:]·W[o,:] + bias[o]
//     d[b,o]   = sum_i (diag_sigma[b,i] + mu[b,i]^2) * sp[o,i] + (o==b)*sbias[o]
// One thread per o, transposed coalesced fp32 loads, no cross-lane reduction.
// ---------------------------------------------------------------------------
__global__ __launch_bounds__(384) void k2_kernel(const float* __restrict__ mu,
                                                 const float* __restrict__ bias,
                                                 const float* __restrict__ sbias,
                                                 float* __restrict__ out_muf) {
    const int b = blockIdx.x;
    const int t = threadIdx.x;   // = o
    __shared__ __align__(16) float muL[INn];
    __shared__ __align__(16) float tL[INn];
    for (int i = t; i < INn; i += 384) {
        float m = mu[b * INn + i];
        muL[i] = m;
        tL[i] = g_t[b * INn + i] + m * m;
    }
    __syncthreads();
    float mf = 0.f, dd = 0.f;
#pragma unroll 8
    for (int i = 0; i < INn; ++i) {
        mf += g_Wt[i * OUTn + t] * muL[i];
        dd += g_spt[i * OUTn + t] * tL[i];
    }
    out_muf[b * OUTn + t] = mf + bias[t];
    g_d[b * OUTn + t] = dd + (t == b ? sbias[t] : 0.f);
}

// ---------------------------------------------------------------------------
// passB: out[b,o,p0+p] = sum_i W[o,i] * U[b,p0+p,i]  (+ d[b,o] if o==p)
// grid (6 p-tiles of 64, 384 b), 512 thr = 8 waves. NO LDS, NO barriers.
//  - A (W frags) from g_Wf: 1KB contiguous per instr, L2-resident.
//  - B (U frags) straight from U2: per instr 4 fully-used 128B lines; all 8
//    waves share the same 64KB tile -> L1/L2 hits; HBM reads U exactly once.
// ---------------------------------------------------------------------------
__global__ __launch_bounds__(512, 4) void passB_kernel(float* __restrict__ outS) {
    const int ptile = blockIdx.x;   // 0..5
    const int b     = blockIdx.y;   // 0..383
    const int tid   = threadIdx.x;
    const int wave  = tid >> 6, lane = tid & 63;
    const int quad  = lane >> 4, l15 = lane & 15;
    const int p0     = ptile * 64;
    const int o_base = wave * 48;   // 8 waves x 48 = 384 o

    const __bf16* Ub = g_U + (size_t)b * (OUTn * INn);

    f32x4 acc[3][4];
#pragma unroll
    for (int mi = 0; mi < 3; ++mi)
#pragma unroll
        for (int nf = 0; nf < 4; ++nf) acc[mi][nf] = (f32x4){0.f, 0.f, 0.f, 0.f};

    for (int kc = 0; kc < INn; kc += 32) {
        bf16x8 afr[3];
#pragma unroll
        for (int mi = 0; mi < 3; ++mi) {
            const int ot = wave * 3 + mi;
            const __bf16* ap = g_Wf + ((((size_t)(ot * 16 + (kc >> 5)) * 4 + quad) * 16 + l15) << 3);
            afr[mi] = *(const bf16x8*)ap;
        }
        const int i4 = (kc >> 2) + quad * 2;
#pragma unroll
        for (int nf = 0; nf < 4; ++nf) {
            const int p = p0 + nf * 16 + l15;
            bf16x4 lo = *(const bf16x4*)(Ub + ((size_t)i4 * OUTn + p) * 4);
            bf16x4 hi = *(const bf16x4*)(Ub + ((size_t)(i4 + 1) * OUTn + p) * 4);
            bf16x8 bfr;
            bfr[0]=lo[0]; bfr[1]=lo[1]; bfr[2]=lo[2]; bfr[3]=lo[3];
            bfr[4]=hi[0]; bfr[5]=hi[1]; bfr[6]=hi[2]; bfr[7]=hi[3];
#pragma unroll
            for (int mi = 0; mi < 3; ++mi)
                acc[mi][nf] = __builtin_amdgcn_mfma_f32_16x16x32_bf16(afr[mi], bfr, acc[mi][nf], 0, 0, 0);
        }
    }

    // ---- epilogue: add diagonal, store fp32 (full 64B sectors) ----
    float* outb = outS + (size_t)b * (OUTn * OUTn);
#pragma unroll
    for (int mi = 0; mi < 3; ++mi) {
        const int o_r = o_base + mi * 16 + quad * 4;
#pragma unroll
        for (int nf = 0; nf < 4; ++nf) {
            const int p = p0 + nf * 16 + l15;
#pragma unroll
            for (int r = 0; r < 4; ++r) {
                const int o = o_r + r;
                float v = acc[mi][nf][r];
                if (o == p) v += g_d[b * OUTn + o];
                outb[(size_t)o * OUTn + p] = v;
            }
        }
    }
}

// ---------------------------------------------------------------------------
extern "C" void kernel_launch(void* const* d_in, const int* in_sizes, int n_in,
                              void* d_out, int out_size, void* d_ws, size_t ws_size,
                              hipStream_t stream) {
    const float* mu    = (const float*)d_in[0];
    const float* sigma = (const float*)d_in[1];
    const float* W     = (const float*)d_in[2];
    const float* bias  = (const float*)d_in[3];
    const float* sw    = (const float*)d_in[4];
    const float* sbias = (const float*)d_in[5];

    float* out     = (float*)d_out;
    float* out_muf = out;                  // [384, 384]
    float* out_sig = out + Bn * OUTn;      // [384, 384, 384]

    prep_kernel<<<(OUTn * INn + 255) / 256, 256, 0, stream>>>(W, sw);
    passA_kernel<<<dim3(8, Bn), 512, 0, stream>>>(sigma);                    // g_U, g_t
    k2_kernel<<<Bn, 384, 0, stream>>>(mu, bias, sbias, out_muf);             // g_d
    passB_kernel<<<dim3(6, Bn), 512, 0, stream>>>(out_sig);
}